// Round 2
// baseline (1050.290 us; speedup 1.0000x reference)
//
#include <hip/hip_runtime.h>
#include <stdint.h>

typedef uint16_t u16;
typedef uint32_t u32;
typedef __attribute__((ext_vector_type(4))) float f32x4;
typedef __attribute__((ext_vector_type(4))) u32 u32x4;
typedef __attribute__((ext_vector_type(8))) u16 u16x8;
typedef __attribute__((ext_vector_type(8))) short s16x8;

#define MFMA16(ACC, A, B) \
  ACC = __builtin_amdgcn_mfma_f32_16x16x32_bf16( \
      __builtin_bit_cast(s16x8, A), __builtin_bit_cast(s16x8, B), ACC, 0, 0, 0)

__device__ __forceinline__ u16 f2bf(float f) {
  __bf16 h = (__bf16)f;                       // RNE
  return __builtin_bit_cast(u16, h);
}
__device__ __forceinline__ float bf2f(u16 h) {
  u32 u = ((u32)h) << 16;
  return __builtin_bit_cast(float, u);
}

// ---------------------------------------------------------------------------
// GEMM: C[M,N] = A[M,K] * B[N,K]^T   (nn.Linear with row-major weight)
// A: fp32 (ABF16=0) or bf16 (ABF16=1).  B: fp32.  C: bf16 (CF32=0) or fp32.
// 128x128 tile, BK=32, 4 waves (2x2 of 64x64), 16x16x32 bf16 MFMA.
// ---------------------------------------------------------------------------
template <int ABF16, int CF32>
__global__ __launch_bounds__(256) void gemm_bt(const void* __restrict__ Av,
                                               const float* __restrict__ B,
                                               void* __restrict__ Cv,
                                               int M, int N, int K,
                                               int lda, int ldb, int ldc) {
  __shared__ __align__(16) u16 As[128 * 40];
  __shared__ __align__(16) u16 Bs[128 * 40];
  const int t = threadIdx.x;
  const int lane = t & 63;
  const int wid = t >> 6;
  const int c = lane & 15;
  const int g = lane >> 4;
  const int wr = wid >> 1, wc = wid & 1;
  const int m0 = blockIdx.x * 128, n0 = blockIdx.y * 128;

  const int srow = t >> 1;   // 0..127 staging row
  const int shalf = t & 1;   // which 16-elem half of BK=32
  int arow = m0 + srow; if (arow >= M) arow = M - 1;   // clamp M edge
  const int brow = n0 + srow;

  f32x4 acc[4][4];
#pragma unroll
  for (int i = 0; i < 4; ++i)
#pragma unroll
    for (int j = 0; j < 4; ++j) acc[i][j] = (f32x4){0.f, 0.f, 0.f, 0.f};

  for (int k0 = 0; k0 < K; k0 += 32) {
    __syncthreads();
    const int col = k0 + shalf * 16;
    u16x8 wa0, wa1, wb0, wb1;
    if (ABF16) {
      const u16x8* ap = (const u16x8*)((const u16*)Av + (size_t)arow * lda + col);
      wa0 = ap[0]; wa1 = ap[1];
    } else {
      const float* ap = (const float*)Av + (size_t)arow * lda + col;
#pragma unroll
      for (int i = 0; i < 8; ++i) wa0[i] = f2bf(ap[i]);
#pragma unroll
      for (int i = 0; i < 8; ++i) wa1[i] = f2bf(ap[8 + i]);
    }
    {
      const float* bp = B + (size_t)brow * ldb + col;
#pragma unroll
      for (int i = 0; i < 8; ++i) wb0[i] = f2bf(bp[i]);
#pragma unroll
      for (int i = 0; i < 8; ++i) wb1[i] = f2bf(bp[8 + i]);
    }
    *(u16x8*)&As[srow * 40 + shalf * 16]     = wa0;
    *(u16x8*)&As[srow * 40 + shalf * 16 + 8] = wa1;
    *(u16x8*)&Bs[srow * 40 + shalf * 16]     = wb0;
    *(u16x8*)&Bs[srow * 40 + shalf * 16 + 8] = wb1;
    __syncthreads();

    u16x8 af[4], bf[4];
#pragma unroll
    for (int mf = 0; mf < 4; ++mf)
      af[mf] = *(const u16x8*)&As[(wr * 64 + mf * 16 + c) * 40 + g * 8];
#pragma unroll
    for (int nf = 0; nf < 4; ++nf)
      bf[nf] = *(const u16x8*)&Bs[(wc * 64 + nf * 16 + c) * 40 + g * 8];
#pragma unroll
    for (int mf = 0; mf < 4; ++mf)
#pragma unroll
      for (int nf = 0; nf < 4; ++nf) MFMA16(acc[mf][nf], af[mf], bf[nf]);
  }

#pragma unroll
  for (int mf = 0; mf < 4; ++mf) {
#pragma unroll
    for (int nf = 0; nf < 4; ++nf) {
      const int colo = n0 + wc * 64 + nf * 16 + c;
#pragma unroll
      for (int r = 0; r < 4; ++r) {
        const int row = m0 + wr * 64 + mf * 16 + 4 * g + r;
        if (row < M) {
          if (CF32) ((float*)Cv)[(size_t)row * ldc + colo] = acc[mf][nf][r];
          else      ((u16*)Cv)[(size_t)row * ldc + colo]   = f2bf(acc[mf][nf][r]);
        }
      }
    }
  }
}

// ---------------------------------------------------------------------------
// Per-128-chunk RMSNorm, in place on bf16 buffer. One wave per chunk.
// ---------------------------------------------------------------------------
__global__ __launch_bounds__(256) void rms128(u16* __restrict__ X,
                                              const float* __restrict__ W,
                                              int nchunks) {
  const int lane = threadIdx.x & 63;
  const int chunk = blockIdx.x * 4 + (threadIdx.x >> 6);
  if (chunk >= nchunks) return;
  u32* p = (u32*)X + (size_t)chunk * 64 + lane;
  const u32 v = *p;
  const float f0 = bf2f((u16)(v & 0xFFFFu));
  const float f1 = bf2f((u16)(v >> 16));
  float ss = f0 * f0 + f1 * f1;
#pragma unroll
  for (int m = 1; m < 64; m <<= 1) ss += __shfl_xor(ss, m, 64);
  const float r = rsqrtf(ss * (1.0f / 128.0f) + 1e-5f);
  const float w0 = W[2 * lane], w1 = W[2 * lane + 1];
  const u32 o = (u32)f2bf(f0 * r * w0) | ((u32)f2bf(f1 * r * w1) << 16);
  *p = o;
}

// ---------------------------------------------------------------------------
// GQA flash attention. Block = (q-tile 64, head, batch); 4 waves x 16 q-rows.
// Swapped QK^T (mfma(K,Q)) so softmax row-reduce is 2 shuffles; P staged in
// per-wave LDS (syncthreads-fenced). K tile XOR-swizzled (16B blocks) to kill
// the D=128 row-major bank conflict. V staged transposed [d][k].
// ---------------------------------------------------------------------------
__global__ __launch_bounds__(256) void attn_fwd(const u16* __restrict__ Qb,
                                                const u16* __restrict__ Kb,
                                                const u16* __restrict__ Vb,
                                                u16* __restrict__ Ob,
                                                const int* __restrict__ cuq,
                                                const int* __restrict__ cuk) {
  __shared__ __align__(16) u16 Klds[32 * 128];   // swizzled row-major [32][128]
  __shared__ __align__(16) u16 Vt[128 * 40];     // V^T [d=128][k=32], stride 40
  __shared__ __align__(16) u16 Plds[4][16 * 40]; // per-wave P [q=16][k=32], stride 40

  const int t = threadIdx.x;
  const int lane = t & 63;
  const int wid = t >> 6;
  const int c = lane & 15;
  const int g = lane >> 4;
  const int qt = blockIdx.x;   // 0..3
  const int h = blockIdx.y;    // 0..31
  const int b = blockIdx.z;    // 0..3
  const int kvh = h >> 2;      // GQA group

  const int qstart = cuq[b];
  const int kstart = cuk[b];
  const int klen = cuk[b + 1] - kstart;
  const int q0w = qstart + qt * 64 + wid * 16;

  // Q fragments (B-operand: n = lane&15 = q-row, k = d). Held in regs.
  u16x8 qf[4];
#pragma unroll
  for (int c4 = 0; c4 < 4; ++c4)
    qf[c4] = *(const u16x8*)(Qb + (size_t)(q0w + c) * 4096 + h * 128 + c4 * 32 + g * 8);

  f32x4 o[8];
#pragma unroll
  for (int i = 0; i < 8; ++i) o[i] = (f32x4){0.f, 0.f, 0.f, 0.f};
  float mrun = -1e30f, lrun = 0.f;

  const int kr = t >> 3;        // K stage: row 0..31
  const int kb2 = (t & 7) * 2;  // K stage: 16B block pair
  const int vk = t & 31;        // V stage: key
  const int vd = t >> 5;        // V stage: d-chunk 0..7

  const int nsteps = (klen + 31) >> 5;
  constexpr float CSC = 0.08838834764831845f * 1.4426950408889634f; // scale * log2(e)

  for (int s = 0; s < nsteps; ++s) {
    const int kv0 = s * 32;
    __syncthreads();
    { // K stage, XOR-swizzle 16B blocks within each 256B row
      int krow = kv0 + kr; if (krow >= klen) krow = klen - 1;
      const u32x4* gp = (const u32x4*)(Kb + (size_t)(kstart + krow) * 1024 + kvh * 128 + kb2 * 8);
      u32x4 d0 = gp[0], d1 = gp[1];
      const int sw = kr & 7;
      *(u32x4*)&Klds[kr * 128 + ((kb2) ^ sw) * 8]     = d0;
      *(u32x4*)&Klds[kr * 128 + ((kb2 + 1) ^ sw) * 8] = d1;
    }
    { // V stage, transposed
      int vrow = kv0 + vk; if (vrow >= klen) vrow = klen - 1;
      const u16* gp = Vb + (size_t)(kstart + vrow) * 1024 + kvh * 128 + vd * 16;
      u16x8 v0 = *(const u16x8*)gp;
      u16x8 v1 = *(const u16x8*)(gp + 8);
#pragma unroll
      for (int j = 0; j < 8; ++j) Vt[(vd * 16 + j) * 40 + vk] = v0[j];
#pragma unroll
      for (int j = 0; j < 8; ++j) Vt[(vd * 16 + 8 + j) * 40 + vk] = v1[j];
    }
    __syncthreads();

    // S^T[key, q] = K · Q^T
    f32x4 sacc[2];
    sacc[0] = (f32x4){0.f, 0.f, 0.f, 0.f};
    sacc[1] = (f32x4){0.f, 0.f, 0.f, 0.f};
#pragma unroll
    for (int kf = 0; kf < 2; ++kf) {
      const int row = kf * 16 + c;
      const int sw = row & 7;
#pragma unroll
      for (int c4 = 0; c4 < 4; ++c4) {
        u16x8 a = *(const u16x8*)&Klds[row * 128 + ((c4 * 4 + g) ^ sw) * 8];
        MFMA16(sacc[kf], a, qf[c4]);
      }
    }

    // masked, scaled scores; row (=q) reduce across the 4 lane-groups
    float tv[8];
    float tmax = -1e30f;
#pragma unroll
    for (int kf = 0; kf < 2; ++kf)
#pragma unroll
      for (int r = 0; r < 4; ++r) {
        const int key = kv0 + kf * 16 + 4 * g + r;
        float x = sacc[kf][r] * CSC;
        x = (key < klen) ? x : -1e30f;
        tv[kf * 4 + r] = x;
        tmax = fmaxf(tmax, x);
      }
    tmax = fmaxf(tmax, __shfl_xor(tmax, 16, 64));
    tmax = fmaxf(tmax, __shfl_xor(tmax, 32, 64));
    const float mnew = fmaxf(mrun, tmax);
    const float fsc = __builtin_amdgcn_exp2f(mrun - mnew);
    mrun = mnew;

    float ps = 0.f;
    u16* Pw = Plds[wid];
#pragma unroll
    for (int kf = 0; kf < 2; ++kf)
#pragma unroll
      for (int r = 0; r < 4; ++r) {
        const float p = __builtin_amdgcn_exp2f(tv[kf * 4 + r] - mnew);
        ps += p;
        Pw[c * 40 + kf * 16 + 4 * g + r] = f2bf(p);
      }
    ps += __shfl_xor(ps, 16, 64);
    ps += __shfl_xor(ps, 32, 64);
    lrun = lrun * fsc + ps;

    // O rescale: O rows are q = 4g+r; pull factor from column-lane q
    float fr[4];
#pragma unroll
    for (int r = 0; r < 4; ++r) fr[r] = __shfl(fsc, 4 * g + r, 64);
#pragma unroll
    for (int nf = 0; nf < 8; ++nf)
#pragma unroll
      for (int r = 0; r < 4; ++r) o[nf][r] *= fr[r];

    __syncthreads();  // fence P ds_writes before the ds_read below (paranoia)
    u16x8 ap = *(const u16x8*)&Pw[c * 40 + g * 8];
#pragma unroll
    for (int nf = 0; nf < 8; ++nf) {
      u16x8 bv = *(const u16x8*)&Vt[(nf * 16 + c) * 40 + g * 8];
      MFMA16(o[nf], ap, bv);
    }
  }

  float linv[4];
#pragma unroll
  for (int r = 0; r < 4; ++r) {
    const float lr = __shfl(lrun, 4 * g + r, 64);
    linv[r] = 1.0f / lr;
  }
#pragma unroll
  for (int nf = 0; nf < 8; ++nf)
#pragma unroll
    for (int r = 0; r < 4; ++r) {
      const int row = q0w + 4 * g + r;
      Ob[(size_t)row * 4096 + h * 128 + nf * 16 + c] = f2bf(o[nf][r] * linv[r]);
    }
}

// ---------------------------------------------------------------------------
extern "C" void kernel_launch(void* const* d_in, const int* in_sizes, int n_in,
                              void* d_out, int out_size, void* d_ws, size_t ws_size,
                              hipStream_t stream) {
  (void)in_sizes; (void)n_in; (void)out_size; (void)ws_size;
  const float* hidden = (const float*)d_in[0];
  const float* cross  = (const float*)d_in[1];
  const float* Wq = (const float*)d_in[2];
  const float* Wk = (const float*)d_in[3];
  const float* Wv = (const float*)d_in[4];
  const float* Wo = (const float*)d_in[5];
  const float* qw = (const float*)d_in[6];
  const float* kw = (const float*)d_in[7];
  const int* cuq = (const int*)d_in[8];
  const int* cuk = (const int*)d_in[9];

  const int Tq = 1024, Tk = 6404;
  u16* Qb = (u16*)d_ws;                        // [1024,4096] bf16
  u16* Kb = Qb + (size_t)Tq * 4096;            // [6404,1024] bf16
  u16* Vb = Kb + (size_t)Tk * 1024;            // [6404,1024] bf16
  u16* Ob = Vb + (size_t)Tk * 1024;            // [1024,4096] bf16
  // total ws use: 43,008,000 bytes

  gemm_bt<0, 0><<<dim3(8, 32),  256, 0, stream>>>(hidden, Wq, Qb, Tq, 4096, 4096, 4096, 4096, 4096);
  gemm_bt<0, 0><<<dim3(51, 8),  256, 0, stream>>>(cross,  Wk, Kb, Tk, 1024, 4096, 4096, 4096, 1024);
  gemm_bt<0, 0><<<dim3(51, 8),  256, 0, stream>>>(cross,  Wv, Vb, Tk, 1024, 4096, 4096, 4096, 1024);
  rms128<<<dim3(32768 / 4), 256, 0, stream>>>(Qb, qw, 32768);
  rms128<<<dim3(51232 / 4), 256, 0, stream>>>(Kb, kw, 51232);
  attn_fwd<<<dim3(4, 32, 4), 256, 0, stream>>>(Qb, Kb, Vb, Ob, cuq, cuk);
  gemm_bt<1, 1><<<dim3(8, 32),  256, 0, stream>>>(Ob, Wo, (float*)d_out, Tq, 4096, 4096, 4096, 4096, 4096);
}